// Round 8
// baseline (56.553 us; speedup 1.0000x reference)
//
#include <hip/hip_runtime.h>

#define G 7
#define CCH 256
#define NLVL 6

__device__ __constant__ int kD[NLVL]  = {38, 19, 10, 5, 3, 1};
__device__ __constant__ int kD2[NLVL] = {1444, 361, 100, 25, 9, 1};
// base offset (in floats) of each level inside the transposed fmap buffer
__device__ __constant__ int kBaseT[NLVL + 1] = {0, 369664, 462080, 487680, 494080, 496384, 496640};

#define FMT_TOTAL 496640  // floats

// ---------------- kernel 1: transpose fmaps [C][D*D] -> [D*D][C] ----------------
__global__ __launch_bounds__(256) void transpose_fmaps(
    const float* __restrict__ f0, const float* __restrict__ f1,
    const float* __restrict__ f2, const float* __restrict__ f3,
    const float* __restrict__ f4, const float* __restrict__ f5,
    float* __restrict__ fmT)
{
    int o = blockIdx.x * blockDim.x + threadIdx.x;
    if (o >= FMT_TOTAL) return;
    int l = 0;
#pragma unroll
    for (int k = 1; k < NLVL; ++k) l += (o >= kBaseT[k]);
    int rel = o - kBaseT[l];
    int p = rel >> 8;        // position within D*D
    int c = rel & 255;       // channel
    const float* f;
    switch (l) {
        case 0: f = f0; break;
        case 1: f = f1; break;
        case 2: f = f2; break;
        case 3: f = f3; break;
        case 4: f = f4; break;
        default: f = f5; break;
    }
    fmT[o] = f[c * kD2[l] + p];
}

// ---------------- kernel 2: one block per box, outputs in registers ----------------
__global__ __launch_bounds__(256, 4) void roialign_reg(
    const float* __restrict__ boxes, const float* __restrict__ fmT,
    float* __restrict__ out)
{
    __shared__ int4   sOff[49];   // per-grid-point corner offsets (into fmT)
    __shared__ float4 sW[49];     // per-grid-point bilinear weights

    int n = blockIdx.x;
    int tid = threadIdx.x;        // == channel c

    if (tid < 49) {
        int g = tid;
        float bx1 = boxes[n * 4 + 0];
        float by1 = boxes[n * 4 + 1];
        float bx2 = boxes[n * 4 + 2];
        float by2 = boxes[n * 4 + 3];
        float w = bx2 - bx1;
        float h = by2 - by1;
        // level: clip(floor(5 + log2(sqrt(w*h))), 0, 5), same f32 op order as ref
        float avg = sqrtf(w * h);
        float lf = floorf((float)(NLVL - 1) + log2f(avg));
        lf = fminf(fmaxf(lf, 0.0f), (float)(NLVL - 1));
        int lvl = (int)lf;
        int D = kD[lvl];
        float Dm1 = (float)(D - 1);
        int base = kBaseT[lvl];

        int i = g / 7;
        int j = g - i * 7;
        float xr = fminf(fmaxf(bx1 + ((float)i * w) / 6.0f, 0.0f), 1.0f);
        float yr = fminf(fmaxf(by1 + ((float)j * h) / 6.0f, 0.0f), 1.0f);
        float ux = xr * Dm1;
        float uy = yr * Dm1;
        float x0 = floorf(ux);
        float y0 = floorf(uy);
        int ix0 = (int)x0;
        int iy0 = (int)y0;
        float fx = ux - x0;   // px1
        float fy = uy - y0;   // py1
        int ix1 = min(ix0 + 1, D - 1);
        int iy1 = min(iy0 + 1, D - 1);

        sOff[g] = make_int4(base + (ix0 * D + iy0) * CCH,
                            base + (ix1 * D + iy0) * CCH,
                            base + (ix0 * D + iy1) * CCH,
                            base + (ix1 * D + iy1) * CCH);
        float px0 = 1.0f - fx, py0 = 1.0f - fy;
        sW[g] = make_float4(px0 * py0, fx * py0, px0 * fy, fx * fy);
    }
    __syncthreads();

    // ---- gather/FMA: all 49 outputs live in registers (static indices only) ----
    float r[49];
#pragma unroll
    for (int g = 0; g < 49; ++g) {
        int4 o = sOff[g];          // broadcast ds_read_b128, conflict-free
        float4 w4 = sW[g];
        r[g] = w4.x * fmT[o.x + tid] + w4.y * fmT[o.y + tid]
             + w4.z * fmT[o.z + tid] + w4.w * fmT[o.w + tid];
    }

    // ---- writeback: 49 floats per lane at byte stride 196 (4B-aligned 16B stores) ----
    char* dst = (char*)(out + (size_t)n * (CCH * G * G) + tid * 49);
#pragma unroll
    for (int k = 0; k < 12; ++k) {
        float4 v = make_float4(r[4 * k], r[4 * k + 1], r[4 * k + 2], r[4 * k + 3]);
        __builtin_memcpy(dst + 16 * k, &v, 16);
    }
    ((float*)dst)[48] = r[48];
}

// ---------------- fallback (round-2 kernel) if ws too small ----------------
__global__ __launch_bounds__(256) void roialign_fallback(
    const float* __restrict__ boxes,
    const float* __restrict__ f0, const float* __restrict__ f1,
    const float* __restrict__ f2, const float* __restrict__ f3,
    const float* __restrict__ f4, const float* __restrict__ f5,
    float* __restrict__ out, int total4)
{
    int t = blockIdx.x * blockDim.x + threadIdx.x;
    if (t >= total4) return;
    const int perN = CCH * G * G;
    int idx = t * 4;
    int n = idx / perN;
    int rem = idx - n * perN;
    float bx1 = boxes[n * 4 + 0], by1 = boxes[n * 4 + 1];
    float bx2 = boxes[n * 4 + 2], by2 = boxes[n * 4 + 3];
    float w = bx2 - bx1, h = by2 - by1;
    float avg = sqrtf(w * h);
    float lf = floorf((float)(NLVL - 1) + log2f(avg));
    lf = fminf(fmaxf(lf, 0.0f), (float)(NLVL - 1));
    int lvl = (int)lf;
    const float* fm;
    switch (lvl) {
        case 0: fm = f0; break;
        case 1: fm = f1; break;
        case 2: fm = f2; break;
        case 3: fm = f3; break;
        case 4: fm = f4; break;
        default: fm = f5; break;
    }
    int D = kD[lvl];
    float Dm1 = (float)(D - 1);
    float4 res;
    float* rp = &res.x;
#pragma unroll
    for (int k = 0; k < 4; ++k) {
        int e = rem + k;
        int j = e % G;
        int iq = e / G;
        int i = iq % G;
        int c = iq / G;
        float xr = fminf(fmaxf(bx1 + ((float)i * w) / 6.0f, 0.0f), 1.0f);
        float yr = fminf(fmaxf(by1 + ((float)j * h) / 6.0f, 0.0f), 1.0f);
        float ux = xr * Dm1, uy = yr * Dm1;
        float x0 = floorf(ux), y0 = floorf(uy);
        int ix0 = (int)x0, iy0 = (int)y0;
        float fx = ux - x0, fy = uy - y0;
        int ix1 = min(ix0 + 1, D - 1), iy1 = min(iy0 + 1, D - 1);
        const float* p = fm + c * D * D;
        float v00 = p[ix0 * D + iy0], v10 = p[ix1 * D + iy0];
        float v01 = p[ix0 * D + iy1], v11 = p[ix1 * D + iy1];
        float px0 = 1.0f - fx, py0 = 1.0f - fy;
        rp[k] = px0 * py0 * v00 + fx * py0 * v10 + px0 * fy * v01 + fx * fy * v11;
    }
    reinterpret_cast<float4*>(out)[t] = res;
}

extern "C" void kernel_launch(void* const* d_in, const int* in_sizes, int n_in,
                              void* d_out, int out_size, void* d_ws, size_t ws_size,
                              hipStream_t stream) {
    const float* boxes = (const float*)d_in[0];
    const float* f0 = (const float*)d_in[1];
    const float* f1 = (const float*)d_in[2];
    const float* f2 = (const float*)d_in[3];
    const float* f3 = (const float*)d_in[4];
    const float* f4 = (const float*)d_in[5];
    const float* f5 = (const float*)d_in[6];
    float* out = (float*)d_out;
    int N = in_sizes[0] / 4;

    if (ws_size >= (size_t)FMT_TOTAL * sizeof(float)) {
        float* fmT = (float*)d_ws;
        transpose_fmaps<<<(FMT_TOTAL + 255) / 256, 256, 0, stream>>>(
            f0, f1, f2, f3, f4, f5, fmT);
        roialign_reg<<<N, 256, 0, stream>>>(boxes, fmT, out);
    } else {
        int total4 = out_size / 4;
        roialign_fallback<<<(total4 + 255) / 256, 256, 0, stream>>>(
            boxes, f0, f1, f2, f3, f4, f5, out, total4);
    }
}

// Round 9
// 43.485 us; speedup vs baseline: 1.3005x; 1.3005x over previous
//
#include <hip/hip_runtime.h>

#define G 7
#define CCH 256
#define NLVL 6

__device__ __constant__ int kD[NLVL]  = {38, 19, 10, 5, 3, 1};
__device__ __constant__ int kD2[NLVL] = {1444, 361, 100, 25, 9, 1};
// base offset (in floats) of each level inside the transposed fmap buffer
__device__ __constant__ int kBaseT[NLVL + 1] = {0, 369664, 462080, 487680, 494080, 496384, 496640};

#define FMT_TOTAL 496640                    // floats
#define TBL_BYTES_PER (32)                  // int4 + float4
#define WS_NEEDED (FMT_TOTAL * 4 + 2000 * 49 * TBL_BYTES_PER)

struct BoxTab { int4 o; float4 w; };        // 32 B

// ---------------- kernel 1: transpose fmaps [C][D*D] -> [D*D][C] ----------------
__global__ __launch_bounds__(256) void transpose_fmaps(
    const float* __restrict__ f0, const float* __restrict__ f1,
    const float* __restrict__ f2, const float* __restrict__ f3,
    const float* __restrict__ f4, const float* __restrict__ f5,
    float* __restrict__ fmT)
{
    int o = blockIdx.x * blockDim.x + threadIdx.x;
    if (o >= FMT_TOTAL) return;
    int l = 0;
#pragma unroll
    for (int k = 1; k < NLVL; ++k) l += (o >= kBaseT[k]);
    int rel = o - kBaseT[l];
    int p = rel >> 8;        // position within D*D
    int c = rel & 255;       // channel
    const float* f;
    switch (l) {
        case 0: f = f0; break;
        case 1: f = f1; break;
        case 2: f = f2; break;
        case 3: f = f3; break;
        case 4: f = f4; break;
        default: f = f5; break;
    }
    fmT[o] = f[c * kD2[l] + p];
}

// ---------------- kernel 2: per-(box,gridpoint) offset/weight tables ----------------
__global__ __launch_bounds__(256) void make_tables(
    const float* __restrict__ boxes, BoxTab* __restrict__ tbl, int total)
{
    int t = blockIdx.x * blockDim.x + threadIdx.x;
    if (t >= total) return;
    int n = t / 49;
    int g = t - n * 49;

    float bx1 = boxes[n * 4 + 0];
    float by1 = boxes[n * 4 + 1];
    float bx2 = boxes[n * 4 + 2];
    float by2 = boxes[n * 4 + 3];
    float w = bx2 - bx1;
    float h = by2 - by1;
    // level: clip(floor(5 + log2(sqrt(w*h))), 0, 5), same f32 op order as ref
    float avg = sqrtf(w * h);
    float lf = floorf((float)(NLVL - 1) + log2f(avg));
    lf = fminf(fmaxf(lf, 0.0f), (float)(NLVL - 1));
    int lvl = (int)lf;
    int D = kD[lvl];
    float Dm1 = (float)(D - 1);
    int base = kBaseT[lvl];

    int i = g / 7;
    int j = g - i * 7;
    float xr = fminf(fmaxf(bx1 + ((float)i * w) / 6.0f, 0.0f), 1.0f);
    float yr = fminf(fmaxf(by1 + ((float)j * h) / 6.0f, 0.0f), 1.0f);
    float ux = xr * Dm1;
    float uy = yr * Dm1;
    float x0 = floorf(ux);
    float y0 = floorf(uy);
    int ix0 = (int)x0;
    int iy0 = (int)y0;
    float fx = ux - x0;   // px1
    float fy = uy - y0;   // py1
    int ix1 = min(ix0 + 1, D - 1);
    int iy1 = min(iy0 + 1, D - 1);

    BoxTab bt;
    bt.o = make_int4(base + (ix0 * D + iy0) * CCH,
                     base + (ix1 * D + iy0) * CCH,
                     base + (ix0 * D + iy1) * CCH,
                     base + (ix1 * D + iy1) * CCH);
    float px0 = 1.0f - fx, py0 = 1.0f - fy;
    bt.w = make_float4(px0 * py0, fx * py0, px0 * fy, fx * fy);
    tbl[t] = bt;
}

// ---------------- kernel 3: one block per box; SGPR tables; slab writeback ----------------
__global__ __launch_bounds__(256) void roialign_main(
    const BoxTab* __restrict__ tbl, const float* __restrict__ fmT,
    float* __restrict__ out)
{
    __shared__ float sOut[CCH * 49];   // [c][g]; wave w owns floats [w*3136,(w+1)*3136)

    int n = blockIdx.x;
    int tid = threadIdx.x;             // == channel c

    const BoxTab* bt = tbl + n * 49;   // block-uniform -> s_load path

    // ---- gather/FMA: tables via scalar loads, addresses = s[base]+tid*4 ----
#pragma unroll
    for (int g = 0; g < 49; ++g) {
        int4   o  = bt[g].o;           // uniform load (SMEM)
        float4 w4 = bt[g].w;           // uniform load (SMEM)
        float v = w4.x * fmT[o.x + tid] + w4.y * fmT[o.y + tid]
                + w4.z * fmT[o.z + tid] + w4.w * fmT[o.w + tid];
        sOut[tid * 49 + g] = v;        // bank = (49*tid)%32: permutation, conflict-free
    }

    // wave-local DS ordering: slab reads below only touch this wave's own writes
    asm volatile("s_waitcnt lgkmcnt(0)" ::: "memory");
    __builtin_amdgcn_sched_barrier(0);

    // ---- writeback: wave streams its 64-channel slab (784 float4, coalesced) ----
    int wv_id = tid >> 6;
    int lane = tid & 63;
    const float4* s4 = (const float4*)sOut + wv_id * 784;
    float4* out4 = (float4*)(out + (size_t)n * (CCH * G * G)) + wv_id * 784;
#pragma unroll
    for (int k = 0; k < 12; ++k) {
        out4[k * 64 + lane] = s4[k * 64 + lane];
    }
    if (lane < 16) out4[768 + lane] = s4[768 + lane];   // 784 = 12*64 + 16
}

// ---------------- fallback (round-2 kernel) if ws too small ----------------
__global__ __launch_bounds__(256) void roialign_fallback(
    const float* __restrict__ boxes,
    const float* __restrict__ f0, const float* __restrict__ f1,
    const float* __restrict__ f2, const float* __restrict__ f3,
    const float* __restrict__ f4, const float* __restrict__ f5,
    float* __restrict__ out, int total4)
{
    int t = blockIdx.x * blockDim.x + threadIdx.x;
    if (t >= total4) return;
    const int perN = CCH * G * G;
    int idx = t * 4;
    int n = idx / perN;
    int rem = idx - n * perN;
    float bx1 = boxes[n * 4 + 0], by1 = boxes[n * 4 + 1];
    float bx2 = boxes[n * 4 + 2], by2 = boxes[n * 4 + 3];
    float w = bx2 - bx1, h = by2 - by1;
    float avg = sqrtf(w * h);
    float lf = floorf((float)(NLVL - 1) + log2f(avg));
    lf = fminf(fmaxf(lf, 0.0f), (float)(NLVL - 1));
    int lvl = (int)lf;
    const float* fm;
    switch (lvl) {
        case 0: fm = f0; break;
        case 1: fm = f1; break;
        case 2: fm = f2; break;
        case 3: fm = f3; break;
        case 4: fm = f4; break;
        default: fm = f5; break;
    }
    int D = kD[lvl];
    float Dm1 = (float)(D - 1);
    float4 res;
    float* rp = &res.x;
#pragma unroll
    for (int k = 0; k < 4; ++k) {
        int e = rem + k;
        int j = e % G;
        int iq = e / G;
        int i = iq % G;
        int c = iq / G;
        float xr = fminf(fmaxf(bx1 + ((float)i * w) / 6.0f, 0.0f), 1.0f);
        float yr = fminf(fmaxf(by1 + ((float)j * h) / 6.0f, 0.0f), 1.0f);
        float ux = xr * Dm1, uy = yr * Dm1;
        float x0 = floorf(ux), y0 = floorf(uy);
        int ix0 = (int)x0, iy0 = (int)y0;
        float fx = ux - x0, fy = uy - y0;
        int ix1 = min(ix0 + 1, D - 1), iy1 = min(iy0 + 1, D - 1);
        const float* p = fm + c * D * D;
        float v00 = p[ix0 * D + iy0], v10 = p[ix1 * D + iy0];
        float v01 = p[ix0 * D + iy1], v11 = p[ix1 * D + iy1];
        float px0 = 1.0f - fx, py0 = 1.0f - fy;
        rp[k] = px0 * py0 * v00 + fx * py0 * v10 + px0 * fy * v01 + fx * fy * v11;
    }
    reinterpret_cast<float4*>(out)[t] = res;
}

extern "C" void kernel_launch(void* const* d_in, const int* in_sizes, int n_in,
                              void* d_out, int out_size, void* d_ws, size_t ws_size,
                              hipStream_t stream) {
    const float* boxes = (const float*)d_in[0];
    const float* f0 = (const float*)d_in[1];
    const float* f1 = (const float*)d_in[2];
    const float* f2 = (const float*)d_in[3];
    const float* f3 = (const float*)d_in[4];
    const float* f4 = (const float*)d_in[5];
    const float* f5 = (const float*)d_in[6];
    float* out = (float*)d_out;
    int N = in_sizes[0] / 4;

    size_t needed = (size_t)FMT_TOTAL * 4 + (size_t)N * 49 * TBL_BYTES_PER;
    if (ws_size >= needed) {
        float* fmT = (float*)d_ws;
        BoxTab* tbl = (BoxTab*)((char*)d_ws + (size_t)FMT_TOTAL * 4);  // 32B-aligned
        transpose_fmaps<<<(FMT_TOTAL + 255) / 256, 256, 0, stream>>>(
            f0, f1, f2, f3, f4, f5, fmT);
        int total = N * 49;
        make_tables<<<(total + 255) / 256, 256, 0, stream>>>(boxes, tbl, total);
        roialign_main<<<N, 256, 0, stream>>>(tbl, fmT, out);
    } else {
        int total4 = out_size / 4;
        roialign_fallback<<<(total4 + 255) / 256, 256, 0, stream>>>(
            boxes, f0, f1, f2, f3, f4, f5, out, total4);
    }
}

// Round 10
// 35.102 us; speedup vs baseline: 1.6111x; 1.2388x over previous
//
#include <hip/hip_runtime.h>

#define G 7
#define CCH 256
#define NLVL 6

__device__ __constant__ int kD[NLVL]  = {38, 19, 10, 5, 3, 1};
__device__ __constant__ int kD2[NLVL] = {1444, 361, 100, 25, 9, 1};
// base offset (in floats) of each level inside the transposed fmap buffer
__device__ __constant__ int kBaseT[NLVL + 1] = {0, 369664, 462080, 487680, 494080, 496384, 496640};

#define FMT_TOTAL 496640  // floats

// ---------------- kernel 1: transpose fmaps [C][D*D] -> [D*D][C] ----------------
__global__ __launch_bounds__(256) void transpose_fmaps(
    const float* __restrict__ f0, const float* __restrict__ f1,
    const float* __restrict__ f2, const float* __restrict__ f3,
    const float* __restrict__ f4, const float* __restrict__ f5,
    float* __restrict__ fmT)
{
    int o = blockIdx.x * blockDim.x + threadIdx.x;
    if (o >= FMT_TOTAL) return;
    int l = 0;
#pragma unroll
    for (int k = 1; k < NLVL; ++k) l += (o >= kBaseT[k]);
    int rel = o - kBaseT[l];
    int p = rel >> 8;        // position within D*D
    int c = rel & 255;       // channel
    const float* f;
    switch (l) {
        case 0: f = f0; break;
        case 1: f = f1; break;
        case 2: f = f2; break;
        case 3: f = f3; break;
        case 4: f = f4; break;
        default: f = f5; break;
    }
    fmT[o] = f[c * kD2[l] + p];
}

// ---------------- kernel 2: one block per box; 16-channel quarter pipeline ----------------
__global__ __launch_bounds__(256, 8) void roialign_main(
    const float* __restrict__ boxes, const float* __restrict__ fmT,
    float* __restrict__ out)
{
    __shared__ float  slab[4][16 * 49];   // 3136 B per wave slab
    __shared__ int4   sO[49];             // corner offsets (into fmT)
    __shared__ float4 sW4[49];            // bilinear weights

    int n = blockIdx.x;
    int tid = threadIdx.x;

    if (tid < 49) {
        int g = tid;
        float bx1 = boxes[n * 4 + 0];
        float by1 = boxes[n * 4 + 1];
        float bx2 = boxes[n * 4 + 2];
        float by2 = boxes[n * 4 + 3];
        float w = bx2 - bx1;
        float h = by2 - by1;
        // level: clip(floor(5 + log2(sqrt(w*h))), 0, 5), same f32 op order as ref
        float avg = sqrtf(w * h);
        float lf = floorf((float)(NLVL - 1) + log2f(avg));
        lf = fminf(fmaxf(lf, 0.0f), (float)(NLVL - 1));
        int lvl = (int)lf;
        int D = kD[lvl];
        float Dm1 = (float)(D - 1);
        int base = kBaseT[lvl];

        int i = g / 7;
        int j = g - i * 7;
        float xr = fminf(fmaxf(bx1 + ((float)i * w) / 6.0f, 0.0f), 1.0f);
        float yr = fminf(fmaxf(by1 + ((float)j * h) / 6.0f, 0.0f), 1.0f);
        float ux = xr * Dm1;
        float uy = yr * Dm1;
        float x0 = floorf(ux);
        float y0 = floorf(uy);
        int ix0 = (int)x0;
        int iy0 = (int)y0;
        float fx = ux - x0;   // px1
        float fy = uy - y0;   // py1
        int ix1 = min(ix0 + 1, D - 1);
        int iy1 = min(iy0 + 1, D - 1);

        sO[g] = make_int4(base + (ix0 * D + iy0) * CCH,
                          base + (ix1 * D + iy0) * CCH,
                          base + (ix0 * D + iy1) * CCH,
                          base + (ix1 * D + iy1) * CCH);
        float px0 = 1.0f - fx, py0 = 1.0f - fy;
        sW4[g] = make_float4(px0 * py0, fx * py0, px0 * fy, fx * fy);
    }
    __syncthreads();   // the only block-wide barrier

    int wv = tid >> 6;
    int lane = tid & 63;
    int cl = lane & 15;      // channel-local 0..15
    int q  = lane >> 4;      // g-quarter 0..3
    float* ms = slab[wv];
    size_t boxBase = (size_t)n * (CCH * G * G);

#pragma unroll
    for (int h = 0; h < 4; ++h) {
        int cbase = wv * 64 + h * 16;    // 16 channels this quarter
        int c = cbase + cl;

        // gather: lanes cover 16 channels x 4 g-groups
#pragma unroll
        for (int t = 0; t < 13; ++t) {
            int g = q * 13 + t;
            if (g < 49) {
                int4   o  = sO[g];       // 4 distinct b128 broadcast (disjoint banks)
                float4 w4 = sW4[g];
                ms[cl * 49 + g] = w4.x * fmT[o.x + c] + w4.y * fmT[o.y + c]
                                + w4.z * fmT[o.z + c] + w4.w * fmT[o.w + c];
            }
        }

        // slab -> regs (same-wave DS ordering handled by compiler waits)
        const float4* s4 = (const float4*)ms;
        float4 r0 = s4[lane];
        float4 r1 = s4[64 + lane];
        float4 r2 = s4[128 + lane];
        float4 rt;
        if (lane < 4) rt = s4[192 + lane];   // 196 = 3*64 + 4

        // coalesced float4 stores of this 16ch x 49g chunk (3136 B dense)
        float4* o4 = (float4*)(out + boxBase + (size_t)cbase * 49);
        o4[lane] = r0;
        o4[64 + lane] = r1;
        o4[128 + lane] = r2;
        if (lane < 4) o4[192 + lane] = rt;
    }
}

// ---------------- fallback (round-2 kernel) if ws too small ----------------
__global__ __launch_bounds__(256) void roialign_fallback(
    const float* __restrict__ boxes,
    const float* __restrict__ f0, const float* __restrict__ f1,
    const float* __restrict__ f2, const float* __restrict__ f3,
    const float* __restrict__ f4, const float* __restrict__ f5,
    float* __restrict__ out, int total4)
{
    int t = blockIdx.x * blockDim.x + threadIdx.x;
    if (t >= total4) return;
    const int perN = CCH * G * G;
    int idx = t * 4;
    int n = idx / perN;
    int rem = idx - n * perN;
    float bx1 = boxes[n * 4 + 0], by1 = boxes[n * 4 + 1];
    float bx2 = boxes[n * 4 + 2], by2 = boxes[n * 4 + 3];
    float w = bx2 - bx1, h = by2 - by1;
    float avg = sqrtf(w * h);
    float lf = floorf((float)(NLVL - 1) + log2f(avg));
    lf = fminf(fmaxf(lf, 0.0f), (float)(NLVL - 1));
    int lvl = (int)lf;
    const float* fm;
    switch (lvl) {
        case 0: fm = f0; break;
        case 1: fm = f1; break;
        case 2: fm = f2; break;
        case 3: fm = f3; break;
        case 4: fm = f4; break;
        default: fm = f5; break;
    }
    int D = kD[lvl];
    float Dm1 = (float)(D - 1);
    float4 res;
    float* rp = &res.x;
#pragma unroll
    for (int k = 0; k < 4; ++k) {
        int e = rem + k;
        int j = e % G;
        int iq = e / G;
        int i = iq % G;
        int c = iq / G;
        float xr = fminf(fmaxf(bx1 + ((float)i * w) / 6.0f, 0.0f), 1.0f);
        float yr = fminf(fmaxf(by1 + ((float)j * h) / 6.0f, 0.0f), 1.0f);
        float ux = xr * Dm1, uy = yr * Dm1;
        float x0 = floorf(ux), y0 = floorf(uy);
        int ix0 = (int)x0, iy0 = (int)y0;
        float fx = ux - x0, fy = uy - y0;
        int ix1 = min(ix0 + 1, D - 1), iy1 = min(iy0 + 1, D - 1);
        const float* p = fm + c * D * D;
        float v00 = p[ix0 * D + iy0], v10 = p[ix1 * D + iy0];
        float v01 = p[ix0 * D + iy1], v11 = p[ix1 * D + iy1];
        float px0 = 1.0f - fx, py0 = 1.0f - fy;
        rp[k] = px0 * py0 * v00 + fx * py0 * v10 + px0 * fy * v01 + fx * fy * v11;
    }
    reinterpret_cast<float4*>(out)[t] = res;
}

extern "C" void kernel_launch(void* const* d_in, const int* in_sizes, int n_in,
                              void* d_out, int out_size, void* d_ws, size_t ws_size,
                              hipStream_t stream) {
    const float* boxes = (const float*)d_in[0];
    const float* f0 = (const float*)d_in[1];
    const float* f1 = (const float*)d_in[2];
    const float* f2 = (const float*)d_in[3];
    const float* f3 = (const float*)d_in[4];
    const float* f4 = (const float*)d_in[5];
    const float* f5 = (const float*)d_in[6];
    float* out = (float*)d_out;
    int N = in_sizes[0] / 4;

    if (ws_size >= (size_t)FMT_TOTAL * sizeof(float)) {
        float* fmT = (float*)d_ws;
        transpose_fmaps<<<(FMT_TOTAL + 255) / 256, 256, 0, stream>>>(
            f0, f1, f2, f3, f4, f5, fmT);
        roialign_main<<<N, 256, 0, stream>>>(boxes, fmT, out);
    } else {
        int total4 = out_size / 4;
        roialign_fallback<<<(total4 + 255) / 256, 256, 0, stream>>>(
            boxes, f0, f1, f2, f3, f4, f5, out, total4);
    }
}